// Round 5
// baseline (399.798 us; speedup 1.0000x reference)
//
#include <hip/hip_runtime.h>
#include <cstdint>

// ---- types ----
typedef __bf16  bf16;
typedef __bf16  bf16x8 __attribute__((ext_vector_type(8)));
typedef __bf16  bf16x4 __attribute__((ext_vector_type(4)));
typedef __bf16  bf16x2 __attribute__((ext_vector_type(2)));
typedef float   f32x4  __attribute__((ext_vector_type(4)));
typedef float   f32x16 __attribute__((ext_vector_type(16)));

#define GLOAD_LDS16(g, l) __builtin_amdgcn_global_load_lds( \
    (const __attribute__((address_space(1))) void*)(g),     \
    (__attribute__((address_space(3))) void*)(l), 16, 0, 0)

// dims
#define SEQ   2048
#define HID   2048
#define NH    16
#define NKV   8
#define HD    128
#define NQKV  6144   // 4096 q_all + 1024 k + 1024 v
#define MTOT  4096   // B*SEQ

// ---------------- fused prep: convx + all weight transposes ----------------
// Round-5: write side widened 2B -> 16B/lane (gather 8 k from LDS, pack bf16x8;
// bank = (k+n)&31 over the 64 lanes -> 2-way aliasing = free). convx 16B in/out.
__device__ __forceinline__ void transw_body(const float* __restrict__ W, bf16* __restrict__ WT,
                                            int N, int n0, int k0, int t) {
    __shared__ float tile[64][65];
    int tn = t & 63, t4 = t >> 6;
    #pragma unroll
    for (int i = 0; i < 16; ++i) {
        int kk = i * 4 + t4;
        tile[kk][tn] = W[(size_t)(k0 + kk) * N + n0 + tn];
    }
    __syncthreads();
    int tk8 = (t & 7) * 8;        // k base (0..56)
    int tnn = t >> 3;             // n sub-index (0..31)
    #pragma unroll
    for (int i = 0; i < 2; ++i) {
        int nn = i * 32 + tnn;
        bf16x8 o;
        #pragma unroll
        for (int j = 0; j < 8; ++j) o[j] = (bf16)tile[tk8 + j][nn];
        *(bf16x8*)(&WT[(size_t)(n0 + nn) * HID + k0 + tk8]) = o;
    }
}

__global__ __launch_bounds__(256) void prep_kernel(const float* __restrict__ x, bf16* __restrict__ xb,
                                                   const float* __restrict__ Wq, const float* __restrict__ Wk,
                                                   const float* __restrict__ Wv, const float* __restrict__ Wo,
                                                   bf16* __restrict__ wqkvT, bf16* __restrict__ woT) {
    int bx = blockIdx.x, t = threadIdx.x;
    if (bx < 4096) {                                   // convx: 8 f32->bf16 per thread, 16B stores
        int i = bx * 256 + t;
        f32x4 v0 = ((const f32x4*)x)[i * 2];
        f32x4 v1 = ((const f32x4*)x)[i * 2 + 1];
        bf16x8 o;
        o[0] = (bf16)v0[0]; o[1] = (bf16)v0[1]; o[2] = (bf16)v0[2]; o[3] = (bf16)v0[3];
        o[4] = (bf16)v1[0]; o[5] = (bf16)v1[1]; o[6] = (bf16)v1[2]; o[7] = (bf16)v1[3];
        ((bf16x8*)xb)[i] = o;
    } else if (bx < 4096 + 2048) {                     // Wq: N=4096
        int idx = bx - 4096;
        transw_body(Wq, wqkvT, 4096, (idx & 63) * 64, (idx >> 6) * 64, t);
    } else if (bx < 4096 + 2048 + 512) {               // Wk: N=1024
        int idx = bx - (4096 + 2048);
        transw_body(Wk, wqkvT + (size_t)4096 * HID, 1024, (idx & 15) * 64, (idx >> 4) * 64, t);
    } else if (bx < 4096 + 2048 + 1024) {              // Wv: N=1024
        int idx = bx - (4096 + 2048 + 512);
        transw_body(Wv, wqkvT + (size_t)5120 * HID, 1024, (idx & 15) * 64, (idx >> 4) * 64, t);
    } else {                                           // Wo: N=2048
        int idx = bx - (4096 + 2048 + 1024);
        transw_body(Wo, woT, 2048, (idx & 31) * 64, (idx >> 5) * 64, t);
    }
}

// ---------------- MFMA GEMM: C[M,N] = A[M,K] * Bt[N,K]^T ----------------
// 128x128 tile, BK=64, 4 waves (64x64 quadrants), 32x32x16 MFMA.
// (256^2 8-phase experiment concluded NULL rounds 1-3: best 131 µs / 31% MfmaUtil
// vs this kernel's 118 µs / 38% — at 1 block/CU the phase barriers expose the
// LDS+stage path with no co-resident block to hide it.)
template<bool OUT_BF16>
__global__ __launch_bounds__(256) void gemm_bt(const bf16* __restrict__ A, const bf16* __restrict__ Bt,
                                               void* __restrict__ C, int M, int N, int K) {
    __shared__ __align__(16) bf16 As[128 * 64];   // 16 KB
    __shared__ __align__(16) bf16 Bs[128 * 64];   // 16 KB
    const int tid = threadIdx.x;
    const int wave = tid >> 6, lane = tid & 63;
    const int l31 = lane & 31, half = lane >> 5;
    const int tile_n = blockIdx.x * 128, tile_m = blockIdx.y * 128;
    const int wm = (wave & 1) * 64, wn = (wave >> 1) * 64;
    const int sw = l31 & 7;                             // read-side swizzle
    f32x16 acc[2][2] = {};

    for (int k0 = 0; k0 < K; k0 += 64) {
        __syncthreads();
        #pragma unroll
        for (int j = 0; j < 4; ++j) {
            int s = j * 256 + tid;                       // LDS slot 0..1023 (16B each)
            int row = s >> 3, c = s & 7;
            int cs = c ^ (row & 7);                      // fetch permuted chunk
            GLOAD_LDS16(A  + (size_t)(tile_m + row) * K + k0 + (cs << 3), As + (size_t)s * 8);
            GLOAD_LDS16(Bt + (size_t)(tile_n + row) * K + k0 + (cs << 3), Bs + (size_t)s * 8);
        }
        __syncthreads();
        #pragma unroll
        for (int ks = 0; ks < 4; ++ks) {
            int ch = ((ks * 2 + half) ^ sw) << 3;
            bf16x8 a0 = *(const bf16x8*)(As + (size_t)(wm + l31) * 64 + ch);
            bf16x8 a1 = *(const bf16x8*)(As + (size_t)(wm + 32 + l31) * 64 + ch);
            bf16x8 b0 = *(const bf16x8*)(Bs + (size_t)(wn + l31) * 64 + ch);
            bf16x8 b1 = *(const bf16x8*)(Bs + (size_t)(wn + 32 + l31) * 64 + ch);
            acc[0][0] = __builtin_amdgcn_mfma_f32_32x32x16_bf16(a0, b0, acc[0][0], 0, 0, 0);
            acc[0][1] = __builtin_amdgcn_mfma_f32_32x32x16_bf16(a0, b1, acc[0][1], 0, 0, 0);
            acc[1][0] = __builtin_amdgcn_mfma_f32_32x32x16_bf16(a1, b0, acc[1][0], 0, 0, 0);
            acc[1][1] = __builtin_amdgcn_mfma_f32_32x32x16_bf16(a1, b1, acc[1][1], 0, 0, 0);
        }
    }
    // C/D layout (m74/m101): col = lane&31, row = (reg&3) + 8*(reg>>2) + 4*(lane>>5)
    #pragma unroll
    for (int mt = 0; mt < 2; ++mt)
        #pragma unroll
        for (int nt = 0; nt < 2; ++nt)
            #pragma unroll
            for (int reg = 0; reg < 16; ++reg) {
                int row = tile_m + wm + mt * 32 + (reg & 3) + ((reg >> 2) * 8) + half * 4;
                int col = tile_n + wn + nt * 32 + l31;
                float v = acc[mt][nt][reg];
                if (OUT_BF16) ((bf16*)C)[(size_t)row * N + col] = (bf16)v;
                else          ((float*)C)[(size_t)row * N + col] = v;
            }
}

// ---------------- fused post: per-head RMSNorm+RoPE (Q,K) + V transpose ----------------
// Round-5: 16 lanes x bf16x8 per head (16B/lane loads+stores), 16-lane shfl reduce,
// RoPE partner via shfl_xor(2) (d and d+16 are 2 lane-slots apart at 8 elems/lane),
// cos/sin computed once per thread (angle independent of head).
__global__ __launch_bounds__(256) void post_kernel(const bf16* __restrict__ qkv,
                                                   const float* __restrict__ qnw, const float* __restrict__ knw,
                                                   const int* __restrict__ positions,
                                                   bf16* __restrict__ Qh, bf16* __restrict__ Kh,
                                                   bf16* __restrict__ VT) {
    int bx = blockIdx.x;
    if (bx < 4096) {
        int tk = bx;                      // token 0..4095
        int b = tk >> 11, s = tk & 2047;
        int wave = threadIdx.x >> 6, lane = threadIdx.x & 63;
        int g16 = lane >> 4;              // head-slot within wave (0..3)
        int l16 = lane & 15;              // lane within 16-group
        int d0 = l16 * 8;                 // base dim, this lane covers d0..d0+7
        float pos = (float)positions[tk];
        const float L = 1.4533435415278355f;    // log2(theta)/16

        float cv[8], sv[8];
        if (l16 < 4) {                    // only d<32 lanes need trig
            #pragma unroll
            for (int j = 0; j < 8; ++j) {
                float a = pos * exp2f(-(float)((l16 & 1) * 8 + j) * L);
                cv[j] = cosf(a); sv[j] = sinf(a);
            }
        }

        #pragma unroll
        for (int i = 0; i < 2; ++i) {
            int slot = i * 16 + wave * 4 + g16;   // 0..31; 0-15 q heads, 16-23 k heads
            if (slot >= 24) continue;
            bool isq = (slot < 16);
            int h = isq ? slot : slot - 16;
            const bf16* base = qkv + (size_t)tk * NQKV + (isq ? h * 256 : 4096 + h * HD) + d0;
            bf16x8 v = *(const bf16x8*)base;
            float f[8];
            float ssq = 0.0f;
            #pragma unroll
            for (int j = 0; j < 8; ++j) { f[j] = (float)v[j]; ssq += f[j] * f[j]; }
            #pragma unroll
            for (int off = 8; off; off >>= 1) ssq += __shfl_xor(ssq, off);
            float rn = rsqrtf(ssq * (1.0f / 128.0f) + 1e-6f);
            const float* nw = isq ? qnw : knw;
            f32x4 wa = *(const f32x4*)(nw + d0);
            f32x4 wb = *(const f32x4*)(nw + d0 + 4);
            float xv[8];
            #pragma unroll
            for (int j = 0; j < 4; ++j) { xv[j] = f[j] * rn * (1.0f + wa[j]); xv[j + 4] = f[j + 4] * rn * (1.0f + wb[j]); }
            float out[8];
            #pragma unroll
            for (int j = 0; j < 8; ++j) out[j] = xv[j];
            if (l16 < 4) {                // rope on d<32; partner lane-slot is xor 2
                #pragma unroll
                for (int j = 0; j < 8; ++j) {
                    float p = __shfl_xor(xv[j], 2);
                    out[j] = (l16 < 2) ? (xv[j] * cv[j] - p * sv[j])
                                       : (xv[j] * cv[j] + p * sv[j]);
                }
            }
            bf16x8 o;
            #pragma unroll
            for (int j = 0; j < 8; ++j) o[j] = (bf16)out[j];
            bf16* dst = isq ? (Qh + ((size_t)(b * NH + h) * SEQ + s) * HD)
                            : (Kh + ((size_t)(b * NKV + h) * SEQ + s) * HD);
            *(bf16x8*)(dst + d0) = o;
        }
    } else {
        int idx = bx - 4096;              // vtrans: 512 blocks
        int bh = idx >> 5, st = idx & 31;
        int b = bh >> 3, h = bh & 7;
        __shared__ float tile[64][129];
        int t = threadIdx.x;
        const bf16* src = qkv + ((size_t)(b * SEQ) + st * 64) * NQKV + 5120 + h * HD;
        #pragma unroll
        for (int i = 0; i < 32; ++i) {
            int ii = i * 256 + t;
            int tok = ii >> 7, d = ii & 127;
            tile[tok][d] = (float)src[(size_t)tok * NQKV + d];
        }
        __syncthreads();
        bf16* dst = VT + (size_t)(b * NKV + h) * HD * SEQ + st * 64;
        #pragma unroll
        for (int i = 0; i < 32; ++i) {
            int ii = i * 256 + t;
            int d = ii >> 6, sx = ii & 63;
            dst[(size_t)d * SEQ + sx] = (bf16)tile[sx][d];
        }
    }
}

// ---------------- flash attention, Br=128, Bc=64, 8 waves x 16 q-rows ----------------
// 2-phase double-buffered K/V staging (round 4). Round-5: amask via 1 load +
// __ballot per K-tile (was 16 scalar global loads/lane/iter contending the
// vmcnt queue with the staging loads).
__global__ __launch_bounds__(512, 4) void attn_kernel(const bf16* __restrict__ Qh, const bf16* __restrict__ Kh,
                                                      const bf16* __restrict__ VT, const bf16* __restrict__ qkv,
                                                      const int* __restrict__ amask, bf16* __restrict__ attnb) {
    const int bx = blockIdx.x;              // 512 blocks
    const int hb = (bx >> 4) & 31;          // b*16+head
    const int head = hb & 15, b = hb >> 4;
    int q0 = ((bx & 15) + hb) & 15;
    const int qt = (bx & 256) ? (15 - q0) : q0;   // pair sums constant work
    const int kvh = head >> 1;
    __shared__ __align__(16) bf16 Ks[2][64 * 128];  // [buf][row][chunk ^ (row&15)]
    __shared__ __align__(16) bf16 Vs[2][128 * 64];  // [buf][d][chunk ^ (d&7)]
    __shared__ __align__(16) bf16 Ps[8 * 16 * 64];  // per-wave, col ^ ((row>>2)*16)
    const int tid = threadIdx.x, wave = tid >> 6, lane = tid & 63;
    const int quad = lane >> 4, cl = lane & 15;

    // Q fragments in registers: rows qt*128 + wave*16 + cl
    const bf16* qsrc = Qh + ((size_t)(b * NH + head) * SEQ + qt * 128) * HD;
    bf16x8 aq[4];
    #pragma unroll
    for (int kc = 0; kc < 4; ++kc)
        aq[kc] = *(const bf16x8*)(qsrc + (size_t)(wave * 16 + cl) * HD + kc * 32 + quad * 8);

    float lstate[4] = {0.0f, 0.0f, 0.0f, 0.0f};
    f32x4 oacc[8] = {};
    const int qrow_glob = qt * 128 + wave * 16 + quad * 4;  // + r
    // exp2-domain: scale = (1/sqrt(128)) * log2(e); fixed max M = 20
    const float scale = 0.08838834764831845f * 1.4426950408889634f;
    const float M = 20.0f;
    const int kmax = 2 * qt + 1;

    const bf16* kbase = Kh + (size_t)(b * NKV + kvh) * SEQ * HD;
    const bf16* vbase = VT + (size_t)(b * NKV + kvh) * HD * SEQ;

#define STAGE_KV(kt_, buf_) { \
    const bf16* ksrc = kbase + (size_t)(kt_) * 64 * HD; \
    const bf16* vsrc = vbase + (size_t)(kt_) * 64; \
    _Pragma("unroll") \
    for (int j = 0; j < 2; ++j) { \
        int s = j * 512 + tid;                    /* 16B-chunk slot 0..1023 */ \
        int rK = s >> 4, cK = s & 15; \
        GLOAD_LDS16(ksrc + (size_t)rK * HD + ((cK ^ (rK & 15)) << 3), &Ks[buf_][0] + (size_t)s * 8); \
        int dV = s >> 3, cV = s & 7; \
        GLOAD_LDS16(vsrc + (size_t)dV * SEQ + ((cV ^ (dV & 7)) << 3), &Vs[buf_][0] + (size_t)s * 8); \
    } }

    STAGE_KV(0, 0);
    int cur = 0;
    for (int kt = 0; kt <= kmax; ++kt) {
        __syncthreads();                          // stage(kt) landed; buf^1 readers drained
        int mv = amask[b * SEQ + kt * 64 + lane]; // 1 load/lane/tile (was 16)
        if (kt < kmax) STAGE_KV(kt + 1, cur ^ 1); // fly next tile under this tile's compute

        f32x4 sc[4] = {};
        #pragma unroll
        for (int nt = 0; nt < 4; ++nt)
            #pragma unroll
            for (int kc = 0; kc < 4; ++kc) {
                bf16x8 bk = *(const bf16x8*)(&Ks[cur][0] + (size_t)(nt * 16 + cl) * 128 + (((kc * 4 + quad) ^ cl) << 3));
                sc[nt] = __builtin_amdgcn_mfma_f32_16x16x32_bf16(aq[kc], bk, sc[nt], 0, 0, 0);
            }

        unsigned long long mbits = __ballot(mv != 0);   // bit i = amask[kt*64+i]
        #pragma unroll
        for (int nt = 0; nt < 4; ++nt) {
            int kcol = kt * 64 + nt * 16 + cl;
            bool cok = (mbits >> (nt * 16 + cl)) & 1ull;
            #pragma unroll
            for (int r = 0; r < 4; ++r) {
                bool ok = cok && (kcol <= qrow_glob + r);
                float p = ok ? exp2f(sc[nt][r] * scale - M) : 0.0f;
                lstate[r] += p;
                Ps[wave * 1024 + (quad * 4 + r) * 64 + ((nt * 16 + cl) ^ (quad << 4))] = (bf16)p;
            }
        }

        bf16x8 ap[2];
        #pragma unroll
        for (int c = 0; c < 2; ++c)
            ap[c] = *(const bf16x8*)(Ps + wave * 1024 + cl * 64 + ((c * 32 + quad * 8) ^ ((cl >> 2) << 4)));
        #pragma unroll
        for (int n2 = 0; n2 < 8; ++n2)
            #pragma unroll
            for (int c = 0; c < 2; ++c) {
                bf16x8 bv = *(const bf16x8*)(&Vs[cur][0] + (size_t)(n2 * 16 + cl) * 64 + (((c * 4 + quad) ^ (cl & 7)) << 3));
                oacc[n2] = __builtin_amdgcn_mfma_f32_16x16x32_bf16(ap[c], bv, oacc[n2], 0, 0, 0);
            }
        cur ^= 1;
    }
#undef STAGE_KV

    // epilogue: reduce l across the 16 col-lanes once, O/l, sigmoid gate, store
    #pragma unroll
    for (int r = 0; r < 4; ++r) {
        #pragma unroll
        for (int off = 8; off; off >>= 1) lstate[r] += __shfl_xor(lstate[r], off);
        int srow = qt * 128 + wave * 16 + quad * 4 + r;
        float linv = 1.0f / lstate[r];
        #pragma unroll
        for (int n2 = 0; n2 < 8; ++n2) {
            int d = n2 * 16 + cl;
            float g = (float)qkv[(size_t)(b * SEQ + srow) * NQKV + head * 256 + 128 + d];
            float sig = 1.0f / (1.0f + __expf(-g));
            float v = oacc[n2][r] * linv * sig;
            attnb[(size_t)(b * SEQ + srow) * HID + head * HD + d] = (bf16)v;
        }
    }
}

// ---------------- launch ----------------
extern "C" void kernel_launch(void* const* d_in, const int* in_sizes, int n_in,
                              void* d_out, int out_size, void* d_ws, size_t ws_size,
                              hipStream_t stream) {
    const float* x        = (const float*)d_in[0];
    const int*   amask    = (const int*)d_in[1];
    const int*   positions= (const int*)d_in[2];
    const float* Wq       = (const float*)d_in[3];
    const float* Wk       = (const float*)d_in[4];
    const float* Wv       = (const float*)d_in[5];
    const float* Wo       = (const float*)d_in[6];
    const float* qnw      = (const float*)d_in[7];
    const float* knw      = (const float*)d_in[8];
    float* out = (float*)d_out;
    char* ws = (char*)d_ws;

    bf16* xb    = (bf16*)(ws);                         // 16,777,216 B
    bf16* wqkvT = (bf16*)(ws + 16777216);              // 25,165,824 B
    bf16* woT   = (bf16*)(ws + 41943040);              //  8,388,608 B
    bf16* qkv   = (bf16*)(ws + 50331648);              // 50,331,648 B
    bf16* Qh    = (bf16*)(ws + 100663296);             // 16,777,216 B
    bf16* Kh    = (bf16*)(ws + 117440512);             //  8,388,608 B
    bf16* VT    = (bf16*)(ws + 125829120);             //  8,388,608 B
    bf16* attnb = (bf16*)(ws + 134217728);             // 16,777,216 B -> 150,994,944 total

    prep_kernel<<<8192, 256, 0, stream>>>(x, xb, Wq, Wk, Wv, Wo, wqkvT, woT);
    gemm_bt<true><<<dim3(48, 32), 256, 0, stream>>>(xb, wqkvT, qkv, MTOT, NQKV, HID);
    post_kernel<<<4608, 256, 0, stream>>>(qkv, qnw, knw, positions, Qh, Kh, VT);
    attn_kernel<<<512, 512, 0, stream>>>(Qh, Kh, VT, qkv, amask, attnb);
    gemm_bt<false><<<dim3(16, 32), 256, 0, stream>>>(attnb, woT, out, MTOT, HID, HID);

    (void)in_sizes; (void)n_in; (void)out_size; (void)ws_size;
}